// Round 2
// baseline (239.549 us; speedup 1.0000x reference)
//
#include <hip/hip_runtime.h>
#include <math.h>

// Problem constants (from setup_inputs)
#define T_TOTAL 2097152
#define A_DIM   18
#define GAMMA_D 0.99

// Scan blocking: chunk == main-pass tile == block size
#define CHUNK 256
#define NC    (T_TOTAL / CHUNK)        // 8192 chunks
#define KTR   14                       // G^14 ~ 2e-16, G = 0.99^256 ~ 0.076
#define CPB   4                        // chunks per block (consecutive)
#define NB_MAIN (NC / CPB)             // 2048 blocks

// ---------------------------------------------------------------------------
// Fused mega-kernel. Block b owns chunks [4b, 4b+3].
// Phase 1: recompute local discounted sums L for chunks 4b+1 .. 4b+17
//          (the 14-chunk carry lookahead window; G^14 ~ 2e-16) from ep_rs.
//          This removes ALL inter-kernel dependencies: the old k_local and
//          k_carry kernels (and their two graph-serialization points) vanish.
//          Extra ep_rs reads: 18 KB/block, heavily L2-shared with neighbors.
// Phase 2: per chunk — stage 18 KiB weight tile to LDS, in-block f64 suffix
//          scan for d, f32 logsumexp, accumulate {sum d, sum nlp, sum nlp*d}.
__global__ __launch_bounds__(256, 4)
void k_mega(const float* __restrict__ wgt, const int* __restrict__ act,
            const float* __restrict__ r, double* __restrict__ partials) {
    __shared__ float  lds[CHUNK * A_DIM];     // 18 KiB weight tile
    __shared__ double ldsL[17];               // L[4b+1 .. 4b+17]
    __shared__ double ldsC[CPB];              // carry per owned chunk
    __shared__ double ldsT[4];                // per-wave scan totals
    __shared__ double red[12];
    const int tid  = threadIdx.x;
    const int lane = tid & 63, wv = tid >> 6;
    const int c0   = CPB * blockIdx.x;
    const double g    = GAMMA_D;
    const double G_   = pow(g, 256.0);         // per-chunk decay
    const double p    = pow(g, (double)tid);   // g^pos (pos fixed per thread)
    const double ip   = 1.0 / p;               // g^-pos  (<= ~13.0, safe)

    // ---- phase 1: local L for the lookahead window ----
    // wave wv handles k = wv, wv+4, ... < 17; chunk cc = c0+1+k
    const double w4 = pow(g, (double)(4 * lane));
    for (int k = wv; k < 17; k += 4) {
        const int cc = c0 + 1 + k;
        double val = 0.0;
        if (cc < NC) {                         // wave-uniform guard
            const float4 v = ((const float4*)r)[(size_t)cc * 64 + lane];
            val = w4 * ((double)v.x + g * ((double)v.y + g * ((double)v.z + g * (double)v.w)));
            #pragma unroll
            for (int off = 32; off > 0; off >>= 1) val += __shfl_down(val, off, 64);
        }
        if (lane == 0) ldsL[k] = val;
    }
    __syncthreads();
    // carry for chunk c0+i: sum_{m=0}^{13} G^m L[c0+1+i+m]  (i+m <= 16)
    if (tid < CPB) {
        double acc = 0.0, wG = 1.0;
        #pragma unroll
        for (int m = 0; m < KTR; ++m) { acc += wG * ldsL[tid + m]; wG *= G_; }
        ldsC[tid] = acc;                       // published by loop-top sync
    }

    double s_d = 0.0, s_n = 0.0, s_nd = 0.0;

    // ---- phase 2: main per-chunk loop ----
    for (int i = 0; i < CPB; ++i) {
        const int c = c0 + i;
        __syncthreads();                      // protect LDS; publish ldsC/tile
        // stage weight tile (coalesced float4)
        const float4* src = (const float4*)(wgt + (size_t)c * CHUNK * A_DIM);
        float4* dst = (float4*)lds;
        #pragma unroll
        for (int q = 0; q < 5; ++q) {
            int idx = tid + 256 * q;
            if (idx < CHUNK * A_DIM / 4) dst[idx] = src[idx];
        }
        // suffix scan for d (f64, globally scaled by g^pos)
        const int row = c * CHUNK + tid;
        double ss = p * (double)r[row];
        #pragma unroll
        for (int off = 1; off < 64; off <<= 1) {
            double v = __shfl_down(ss, off, 64);
            ss += (lane + off < 64) ? v : 0.0;
        }
        if (lane == 0) ldsT[wv] = ss;         // wave total
        __syncthreads();
        double tail = 0.0;
        #pragma unroll
        for (int m = 0; m < 4; ++m)
            if (m > wv) tail += ldsT[m];
        const double dval = ip * (ss + tail + G_ * ldsC[i]);
        // f32 logsumexp (matches reference dtype; bit-exact so far)
        const float* wr = lds + tid * A_DIM;
        float mx = wr[0];
        #pragma unroll
        for (int j = 1; j < A_DIM; ++j) mx = fmaxf(mx, wr[j]);
        float s = 0.0f;
        #pragma unroll
        for (int j = 0; j < A_DIM; ++j) s += expf(wr[j] - mx);
        const float nlp = mx + logf(s) - wr[act[row]];
        s_d  += dval;
        s_n  += (double)nlp;
        s_nd += (double)nlp * dval;
    }

    // block reduction: 64-lane shuffles, then cross-wave via LDS
    #pragma unroll
    for (int off = 32; off > 0; off >>= 1) {
        s_d  += __shfl_down(s_d,  off, 64);
        s_n  += __shfl_down(s_n,  off, 64);
        s_nd += __shfl_down(s_nd, off, 64);
    }
    if (lane == 0) { red[wv*3+0] = s_d; red[wv*3+1] = s_n; red[wv*3+2] = s_nd; }
    __syncthreads();
    if (tid == 0) {
        double a = 0.0, b = 0.0, cc = 0.0;
        #pragma unroll
        for (int q = 0; q < 4; ++q) { a += red[q*3]; b += red[q*3+1]; cc += red[q*3+2]; }
        partials[blockIdx.x*3+0] = a;
        partials[blockIdx.x*3+1] = b;
        partials[blockIdx.x*3+2] = cc;
    }
}

// ---------------------------------------------------------------------------
// Final reduce: per-block partials -> scalar.
__global__ void k_final(const double* __restrict__ partials, float* __restrict__ out) {
    __shared__ double red[12];
    const int tid = threadIdx.x;
    double a = 0.0, b = 0.0, c = 0.0;
    for (int i = tid; i < NB_MAIN; i += 256) {
        a += partials[i*3+0];
        b += partials[i*3+1];
        c += partials[i*3+2];
    }
    #pragma unroll
    for (int off = 32; off > 0; off >>= 1) {
        a += __shfl_down(a, off, 64);
        b += __shfl_down(b, off, 64);
        c += __shfl_down(c, off, 64);
    }
    const int lane = tid & 63, wv = tid >> 6;
    if (lane == 0) { red[wv*3+0] = a; red[wv*3+1] = b; red[wv*3+2] = c; }
    __syncthreads();
    if (tid == 0) {
        double A_ = 0.0, B_ = 0.0, C_ = 0.0;
        #pragma unroll
        for (int i = 0; i < 4; ++i) { A_ += red[i*3]; B_ += red[i*3+1]; C_ += red[i*3+2]; }
        const double invT = 1.0 / (double)T_TOTAL;
        // out = (1/T) * ( sum(nlp*d) - mean(d) * sum(nlp) )
        out[0] = (float)((C_ - (A_ * invT) * B_) * invT);
    }
}

// ---------------------------------------------------------------------------
extern "C" void kernel_launch(void* const* d_in, const int* in_sizes, int n_in,
                              void* d_out, int out_size, void* d_ws, size_t ws_size,
                              hipStream_t stream) {
    const float* weight = (const float*)d_in[0];   // [T, 18] f32
    const float* ep_rs  = (const float*)d_in[1];   // [T] f32
    const int*   ep_as  = (const int*)  d_in[2];   // [T] int
    float* out = (float*)d_out;

    double* partials = (double*)d_ws;              // NB_MAIN*3 doubles (48 KiB)

    k_mega  <<<NB_MAIN, 256, 0, stream>>>(weight, ep_as, ep_rs, partials);
    k_final <<<1,       256, 0, stream>>>(partials, out);
}